// Round 2
// baseline (2194.849 us; speedup 1.0000x reference)
//
#include <hip/hip_runtime.h>

#define KCAP 96u
#define CAP 6144          // LDS pos-cell list capacity (only L0 can exceed; rare -> fallback)
#define NTOT 344064       // 16*(16384+4096+1024)

__device__ __forceinline__ float softplus_f(float x) {
    return fmaxf(x, 0.0f) + log1pf(expf(-fabsf(x)));
}

// Exact reproduction of the reference geometry (no fma contraction so we
// match XLA's elementwise fp32 at the selection decision boundaries).
__device__ __forceinline__ void tri_pos_dist(
    float px, float py,
    float ax, float ay, float bx, float by, float cx, float cy,
    bool& pos, float& dist)
{
#pragma clang fp contract(off)
    float d1 = (px - bx) * (ay - by) - (ax - bx) * (py - by);
    float d2 = (px - cx) * (by - cy) - (bx - cx) * (py - cy);
    float d3 = (px - ax) * (cy - ay) - (cx - ax) * (py - ay);
    bool has_neg = (d1 < 0.f) | (d2 < 0.f) | (d3 < 0.f);
    bool has_pos = (d1 > 0.f) | (d2 > 0.f) | (d3 > 0.f);
    bool inside = !(has_neg && has_pos);

    float dAB, dBC, dCA;
    {
        float vx = bx - ax, vy = by - ay, wx = px - ax, wy = py - ay;
        float t = (wx*vx + wy*vy) / (vx*vx + vy*vy + 1e-9f);
        t = fminf(fmaxf(t, 0.0f), 1.0f);
        float dx = px - (ax + t*vx), dy = py - (ay + t*vy);
        dAB = sqrtf(dx*dx + dy*dy + 1e-12f);
    }
    {
        float vx = cx - bx, vy = cy - by, wx = px - bx, wy = py - by;
        float t = (wx*vx + wy*vy) / (vx*vx + vy*vy + 1e-9f);
        t = fminf(fmaxf(t, 0.0f), 1.0f);
        float dx = px - (bx + t*vx), dy = py - (by + t*vy);
        dBC = sqrtf(dx*dx + dy*dy + 1e-12f);
    }
    {
        float vx = ax - cx, vy = ay - cy, wx = px - cx, wy = py - cy;
        float t = (wx*vx + wy*vy) / (vx*vx + vy*vy + 1e-9f);
        t = fminf(fmaxf(t, 0.0f), 1.0f);
        float dx = px - (cx + t*vx), dy = py - (cy + t*vy);
        dCA = sqrtf(dx*dx + dy*dy + 1e-12f);
    }
    dist = fminf(dAB, fminf(dBC, dCA));
    pos = inside || (dist <= 3.0f);
}

__global__ void zero_kernel(unsigned* __restrict__ p, int n) {
    int i = blockIdx.x * 256 + threadIdx.x;
    if (i < n) p[i] = 0u;
}

// One block per (level, b, g) pair. Pass 1 evaluates only cells inside the
// ETA-expanded triangle bbox (+1 cell fp-safety margin), histograms the fp32
// bit pattern (positive floats: uint order == float order) AND caches
// (bits, hw) of every pos cell in LDS. Common case: selection + contribution
// run from the cached list with zero re-evaluation. Overflow (>CAP pos cells,
// only possible at level 0, rare) falls back to radix passes over the bbox.
__global__ __launch_bounds__(256) void pair_kernel(
    const float* __restrict__ gt,
    const float* __restrict__ reg0, const float* __restrict__ cls0,
    const float* __restrict__ reg1, const float* __restrict__ cls1,
    const float* __restrict__ reg2, const float* __restrict__ cls2,
    unsigned* __restrict__ objbits,
    double* __restrict__ sums,      // [0]=reg, [1]=cls, [2]=obj
    unsigned* __restrict__ counts)  // [0]=pos_cnt, [1]=objt_cnt
{
    const int bid = blockIdx.x;
    const int level = bid >> 9;        // 512 pairs per level
    const int pair = bid & 511;
    const int b = pair >> 5;

    int W, HW, shift, objbase;
    float stride;
    const float* pr; const float* pcl;
    if (level == 0)      { W = 128; HW = 16384; shift = 7; stride = 8.0f;  objbase = 0;     pr = reg0; pcl = cls0; }
    else if (level == 1) { W = 64;  HW = 4096;  shift = 6; stride = 16.0f; objbase = 8192;  pr = reg1; pcl = cls1; }
    else                 { W = 32;  HW = 1024;  shift = 5; stride = 32.0f; objbase = 10240; pr = reg2; pcl = cls2; }
    const int wmask = W - 1;

    const float* gp = gt + pair * 6;
    const float ax = gp[0], ay = gp[1];
    const float bx = gp[2], by = gp[3];
    const float cx = gp[4], cy = gp[5];

    // ---- expanded bbox of candidate cells (conservative, +1 cell margin) ----
    const float inv = 1.0f / stride;
    float minx = fminf(ax, fminf(bx, cx)), maxx = fmaxf(ax, fmaxf(bx, cx));
    float miny = fminf(ay, fminf(by, cy)), maxy = fmaxf(ay, fmaxf(by, cy));
    int wlo = max(0,     (int)floorf((minx - 3.0f) * inv - 0.5f) - 1);
    int whi = min(W - 1, (int)ceilf ((maxx + 3.0f) * inv - 0.5f) + 1);
    int hlo = max(0,     (int)floorf((miny - 3.0f) * inv - 0.5f) - 1);
    int hhi = min(W - 1, (int)ceilf ((maxy + 3.0f) * inv - 0.5f) + 1);
    const int ncols = whi - wlo + 1;
    const int nb = (hhi - hlo + 1) * ncols;
    const int nbR = (nb + 255) & ~255;

    __shared__ unsigned hist[2048];
    __shared__ unsigned chunk[256];
    __shared__ unsigned s_bits[CAP];
    __shared__ unsigned short s_hw[CAP];
    __shared__ unsigned s_cnt, s_T, s_k, s_mode, s_cnt2;
    __shared__ double red_reg[4], red_cls[4];
    __shared__ unsigned red_pos[4];

    const int tid = threadIdx.x;
    const int lane = tid & 63;
    if (tid == 0) s_cnt = 0u;
    for (int j = tid; j < 2048; j += 256) hist[j] = 0u;
    __syncthreads();

    // ---- pass 1: eval bbox cells once; histogram + cache pos cells ----
    for (int i = tid; i < nbR; i += 256) {
        bool pos = false; unsigned bits = 0u; int hw = 0;
        if (i < nb) {
            int q = i / ncols;
            int w = wlo + (i - q * ncols);
            int h = hlo + q;
            hw = (h << shift) | w;
            float px = (w + 0.5f) * stride;
            float py = (h + 0.5f) * stride;
            float dist;
            tri_pos_dist(px, py, ax, ay, bx, by, cx, cy, pos, dist);
            if (pos) bits = __float_as_uint(dist);
        }
        if (pos) atomicAdd(&hist[bits >> 21], 1u);
        unsigned long long m = __ballot(pos);
        if (m) {
            int leader = __ffsll(m) - 1;
            unsigned base = 0u;
            if (lane == leader) base = atomicAdd(&s_cnt, (unsigned)__popcll(m));
            base = __shfl(base, leader);
            if (pos) {
                unsigned slot = base + (unsigned)__popcll(m & ((1ull << lane) - 1ull));
                if (slot < CAP) { s_bits[slot] = bits; s_hw[slot] = (unsigned short)hw; }
            }
        }
    }
    __syncthreads();

    {   // chunk-reduce the histogram
        unsigned s = 0; int base = tid * 8;
        #pragma unroll
        for (int j = 0; j < 8; ++j) s += hist[base + j];
        chunk[tid] = s;
    }
    __syncthreads();
    if (tid == 0) {
        unsigned total = s_cnt;
        if (total <= KCAP) {
            s_mode = 1u;                       // select everything
        } else {
            s_mode = (total > CAP) ? 2u : 0u;  // overflow -> radix fallback
            unsigned kk = KCAP, cum = 0; int t = 0;
            while (cum + chunk[t] < kk) { cum += chunk[t]; ++t; }
            int bb = t * 8;
            while (cum + hist[bb] < kk) { cum += hist[bb]; ++bb; }
            s_T = (unsigned)bb;
            s_k = kk - cum;
        }
    }
    __syncthreads();
    const unsigned mode = s_mode;

    double regAcc = 0.0, clsAcc = 0.0;
    unsigned posAcc = 0u;

    auto contribute = [&](int hw) {
        int h = hw >> shift, w = hw & wmask;
        float px = (w + 0.5f) * stride;
        float py = (h + 0.5f) * stride;
        const float* base = pr + (size_t)b * 6 * HW + hw;
        float p0x = base[0],          p0y = base[HW];
        float p1x = base[2 * HW],     p1y = base[3 * HW];
        float p2x = base[4 * HW],     p2y = base[5 * HW];
        float g0x = (ax - px) * inv,  g0y = (ay - py) * inv;
        float g1x = (bx - px) * inv,  g1y = (by - py) * inv;
        float g2x = (cx - px) * inv,  g2y = (cy - py) * inv;
        float dx0 = p0x - g0x, dy0 = p0y - g0y;
        float p0t = dx0 * dx0 + dy0 * dy0;
        float e11x = p1x - g1x, e11y = p1y - g1y;
        float e12x = p1x - g2x, e12y = p1y - g2y;
        float e21x = p2x - g1x, e21y = p2y - g1y;
        float e22x = p2x - g2x, e22y = p2y - g2y;
        float d11 = sqrtf(e11x * e11x + e11y * e11y);
        float d12 = sqrtf(e12x * e12x + e12y * e12y);
        float d21 = sqrtf(e21x * e21x + e21y * e21y);
        float d22 = sqrtf(e22x * e22x + e22y * e22y);
        float cd = fminf(d11, d12) + fminf(d21, d22) + fminf(d11, d21) + fminf(d12, d22);
        regAcc += (double)(p0t + cd);
        clsAcc += (double)softplus_f(-pcl[(size_t)b * HW + hw]);
        posAcc += 1u;
        unsigned bi = (unsigned)(b * HW + hw);
        atomicOr(&objbits[objbase + (bi >> 5)], 1u << (bi & 31u));
    };

    if (mode == 1u) {
        // total <= 96: every pos cell selected (all cached)
        unsigned n = s_cnt;
        for (unsigned i = tid; i < n; i += 256) contribute((int)s_hw[i]);
    } else if (mode == 0u) {
        // common case: select from cached list
        unsigned n = s_cnt, T = s_T, k = s_k;
        for (unsigned i = tid; i < n; i += 256) {
            unsigned bi = s_bits[i];
            unsigned bin = bi >> 21;
            if (bin < T) {
                contribute((int)s_hw[i]);
            } else if (bin == T) {
                unsigned hwv = s_hw[i], rank = 0;
                for (unsigned j = 0; j < n; ++j) {
                    unsigned bj = s_bits[j];
                    if ((bj >> 21) == T &&
                        (bj < bi || (bj == bi && s_hw[j] < hwv))) ++rank;
                }
                if (rank < k) contribute((int)s_hw[i]);
            }
        }
    } else {
        // ---- rare fallback: >CAP pos cells; radix passes 2,3 over bbox ----
        unsigned prefix = s_T;
        for (int p = 1; p < 3; ++p) {
            __syncthreads();
            for (int j = tid; j < 2048; j += 256) hist[j] = 0u;
            __syncthreads();
            for (int i = tid; i < nb; i += 256) {
                int q = i / ncols;
                int w = wlo + (i - q * ncols);
                int h = hlo + q;
                float px = (w + 0.5f) * stride;
                float py = (h + 0.5f) * stride;
                bool pos; float dist;
                tri_pos_dist(px, py, ax, ay, bx, by, cx, cy, pos, dist);
                if (!pos) continue;
                unsigned bits = __float_as_uint(dist);
                unsigned bin;
                if (p == 1) { if ((bits >> 21) != prefix) continue; bin = (bits >> 10) & 0x7FFu; }
                else        { if ((bits >> 10) != prefix) continue; bin = bits & 0x3FFu; }
                atomicAdd(&hist[bin], 1u);
            }
            __syncthreads();
            { unsigned s = 0; int base = tid * 8;
              #pragma unroll
              for (int j = 0; j < 8; ++j) s += hist[base + j];
              chunk[tid] = s; }
            __syncthreads();
            if (tid == 0) {
                unsigned kk = s_k, cum = 0; int t = 0;
                while (cum + chunk[t] < kk) { cum += chunk[t]; ++t; }
                int bb = t * 8;
                while (cum + hist[bb] < kk) { cum += hist[bb]; ++bb; }
                s_T = (unsigned)bb;
                s_k = kk - cum;
            }
            __syncthreads();
            prefix = (p == 1) ? ((prefix << 11) | s_T) : ((prefix << 10) | s_T);
        }
        const unsigned kth = prefix, need = s_k;
        if (tid == 0) s_cnt2 = 0u;
        __syncthreads();
        for (int i = tid; i < nb; i += 256) {
            int q = i / ncols;
            int w = wlo + (i - q * ncols);
            int h = hlo + q;
            int hw = (h << shift) | w;
            float px = (w + 0.5f) * stride;
            float py = (h + 0.5f) * stride;
            bool pos; float dist;
            tri_pos_dist(px, py, ax, ay, bx, by, cx, cy, pos, dist);
            if (!pos) continue;
            unsigned bits = __float_as_uint(dist);
            if (bits < kth) {
                contribute(hw);
            } else if (bits == kth) {
                unsigned t = atomicAdd(&s_cnt2, 1u);
                if (t < CAP) s_bits[t] = (unsigned)hw;
            }
        }
        __syncthreads();
        unsigned n = min(s_cnt2, (unsigned)CAP);
        for (unsigned i = tid; i < n; i += 256) {
            unsigned hwv = s_bits[i], rank = 0;
            for (unsigned j = 0; j < n; ++j) rank += (s_bits[j] < hwv) ? 1u : 0u;
            if (rank < need) contribute((int)hwv);
        }
    }

    // ---- block reduce + global accumulate ----
    for (int off = 32; off > 0; off >>= 1) {
        regAcc += __shfl_down(regAcc, off);
        clsAcc += __shfl_down(clsAcc, off);
        posAcc += __shfl_down(posAcc, off);
    }
    int wave = tid >> 6;
    if (lane == 0) { red_reg[wave] = regAcc; red_cls[wave] = clsAcc; red_pos[wave] = posAcc; }
    __syncthreads();
    if (tid == 0) {
        atomicAdd(&sums[0], red_reg[0] + red_reg[1] + red_reg[2] + red_reg[3]);
        atomicAdd(&sums[1], red_cls[0] + red_cls[1] + red_cls[2] + red_cls[3]);
        atomicAdd(&counts[0], red_pos[0] + red_pos[1] + red_pos[2] + red_pos[3]);
    }
}

__global__ __launch_bounds__(256) void obj_kernel(
    const float* __restrict__ o0, const float* __restrict__ o1, const float* __restrict__ o2,
    const unsigned* __restrict__ objbits,
    double* __restrict__ sums, unsigned* __restrict__ counts)
{
    int idx = blockIdx.x * 256 + threadIdx.x;
    double term = 0.0; unsigned tc = 0u;
    if (idx < NTOT) {
        const float* o; int li, lbase;
        if (idx < 262144)      { o = o0; li = idx;          lbase = 0; }
        else if (idx < 327680) { o = o1; li = idx - 262144; lbase = 8192; }
        else                   { o = o2; li = idx - 327680; lbase = 10240; }
        float x = o[li];
        unsigned bit = (objbits[lbase + (li >> 5)] >> (li & 31)) & 1u;
        if (bit) { term = (double)(1.2f * softplus_f(-x)); tc = 1u; }
        else     { term = (double)softplus_f(x); }
    }
    for (int off = 32; off > 0; off >>= 1) {
        term += __shfl_down(term, off);
        tc   += __shfl_down(tc, off);
    }
    __shared__ double rterm[4]; __shared__ unsigned rtc[4];
    int wave = threadIdx.x >> 6, lane = threadIdx.x & 63;
    if (lane == 0) { rterm[wave] = term; rtc[wave] = tc; }
    __syncthreads();
    if (threadIdx.x == 0) {
        atomicAdd(&sums[2], rterm[0] + rterm[1] + rterm[2] + rterm[3]);
        atomicAdd(&counts[1], rtc[0] + rtc[1] + rtc[2] + rtc[3]);
    }
}

__global__ void finalize_kernel(const double* __restrict__ sums,
                                const unsigned* __restrict__ counts,
                                float* __restrict__ out)
{
    double reg = sums[0], cls = sums[1], obj = sums[2];
    double pc  = (double)counts[0];
    double nc  = (double)NTOT - (double)counts[1];
    double pos_eps = fmax(pc, 1.0);
    double den = pos_eps + fmax(nc, 1.0);
    out[0] = (float)(reg / pos_eps + obj / den + cls / pos_eps);
}

extern "C" void kernel_launch(void* const* d_in, const int* in_sizes, int n_in,
                              void* d_out, int out_size, void* d_ws, size_t ws_size,
                              hipStream_t stream)
{
    (void)in_sizes; (void)n_in; (void)out_size; (void)ws_size;
    const float* reg0 = (const float*)d_in[0];
    const float* obj0 = (const float*)d_in[1];
    const float* cls0 = (const float*)d_in[2];
    const float* reg1 = (const float*)d_in[3];
    const float* obj1 = (const float*)d_in[4];
    const float* cls1 = (const float*)d_in[5];
    const float* reg2 = (const float*)d_in[6];
    const float* obj2 = (const float*)d_in[7];
    const float* cls2 = (const float*)d_in[8];
    const float* gt   = (const float*)d_in[9];

    double*   sums    = (double*)d_ws;                       // 3 doubles
    unsigned* counts  = (unsigned*)((char*)d_ws + 24);       // 2 u32
    unsigned* objbits = (unsigned*)((char*)d_ws + 32);       // 10752 u32

    zero_kernel<<<43, 256, 0, stream>>>((unsigned*)d_ws, 10760);
    pair_kernel<<<1536, 256, 0, stream>>>(gt, reg0, cls0, reg1, cls1, reg2, cls2,
                                          objbits, sums, counts);
    obj_kernel<<<1344, 256, 0, stream>>>(obj0, obj1, obj2, objbits, sums, counts);
    finalize_kernel<<<1, 1, 0, stream>>>(sums, counts, (float*)d_out);
}

// Round 3
// 258.217 us; speedup vs baseline: 8.5000x; 8.5000x over previous
//
#include <hip/hip_runtime.h>

#define KCAP 96u
#define TIE_CAP 1024
#define NTOT 344064  // 16*(16384+4096+1024)

__device__ __forceinline__ float softplus_f(float x) {
    return fmaxf(x, 0.0f) + log1pf(expf(-fabsf(x)));
}

// Exact reproduction of the reference geometry (no fma contraction so we
// match XLA's elementwise fp32 at the selection decision boundaries).
__device__ __forceinline__ void tri_pos_dist(
    float px, float py,
    float ax, float ay, float bx, float by, float cx, float cy,
    bool& pos, float& dist)
{
#pragma clang fp contract(off)
    float d1 = (px - bx) * (ay - by) - (ax - bx) * (py - by);
    float d2 = (px - cx) * (by - cy) - (bx - cx) * (py - cy);
    float d3 = (px - ax) * (cy - ay) - (cx - ax) * (py - ay);
    bool has_neg = (d1 < 0.f) | (d2 < 0.f) | (d3 < 0.f);
    bool has_pos = (d1 > 0.f) | (d2 > 0.f) | (d3 > 0.f);
    bool inside = !(has_neg && has_pos);

    float dAB, dBC, dCA;
    {
        float vx = bx - ax, vy = by - ay, wx = px - ax, wy = py - ay;
        float t = (wx*vx + wy*vy) / (vx*vx + vy*vy + 1e-9f);
        t = fminf(fmaxf(t, 0.0f), 1.0f);
        float dx = px - (ax + t*vx), dy = py - (ay + t*vy);
        dAB = sqrtf(dx*dx + dy*dy + 1e-12f);
    }
    {
        float vx = cx - bx, vy = cy - by, wx = px - bx, wy = py - by;
        float t = (wx*vx + wy*vy) / (vx*vx + vy*vy + 1e-9f);
        t = fminf(fmaxf(t, 0.0f), 1.0f);
        float dx = px - (bx + t*vx), dy = py - (by + t*vy);
        dBC = sqrtf(dx*dx + dy*dy + 1e-12f);
    }
    {
        float vx = ax - cx, vy = ay - cy, wx = px - cx, wy = py - cy;
        float t = (wx*vx + wy*vy) / (vx*vx + vy*vy + 1e-9f);
        t = fminf(fmaxf(t, 0.0f), 1.0f);
        float dx = px - (cx + t*vx), dy = py - (cy + t*vy);
        dCA = sqrtf(dx*dx + dy*dy + 1e-12f);
    }
    dist = fminf(dAB, fminf(dBC, dCA));
    pos = inside || (dist <= 3.0f);
}

__global__ void zero_kernel(unsigned* __restrict__ p, int n) {
    int i = blockIdx.x * 256 + threadIdx.x;
    if (i < n) p[i] = 0u;
}

// One block per (level, b, g) pair. Exact top-KCAP smallest dist among pos
// cells via 3-pass radix select on the fp32 bit pattern (positive floats:
// uint order == float order), all passes restricted to the ETA-expanded
// triangle bbox (+1 cell fp-safety margin). Ties at the kth value broken by
// lowest hw index, matching jax.lax.top_k.
__global__ __launch_bounds__(256) void pair_kernel(
    const float* __restrict__ gt,
    const float* __restrict__ reg0, const float* __restrict__ cls0,
    const float* __restrict__ reg1, const float* __restrict__ cls1,
    const float* __restrict__ reg2, const float* __restrict__ cls2,
    unsigned* __restrict__ objbits,
    double* __restrict__ sums,      // [0]=reg, [1]=cls, [2]=obj
    unsigned* __restrict__ counts)  // [0]=pos_cnt, [1]=objt_cnt
{
    const int bid = blockIdx.x;
    const int level = bid >> 9;        // 512 pairs per level
    const int pair = bid & 511;
    const int b = pair >> 5;

    int W, HW, shift, objbase;
    float stride;
    const float* pr; const float* pcl;
    if (level == 0)      { W = 128; HW = 16384; shift = 7; stride = 8.0f;  objbase = 0;     pr = reg0; pcl = cls0; }
    else if (level == 1) { W = 64;  HW = 4096;  shift = 6; stride = 16.0f; objbase = 8192;  pr = reg1; pcl = cls1; }
    else                 { W = 32;  HW = 1024;  shift = 5; stride = 32.0f; objbase = 10240; pr = reg2; pcl = cls2; }
    const int wmask = W - 1;

    const float* gp = gt + pair * 6;
    const float ax = gp[0], ay = gp[1];
    const float bx = gp[2], by = gp[3];
    const float cx = gp[4], cy = gp[5];

    // ---- expanded bbox of candidate cells (conservative, +1 cell margin) ----
    const float inv = 1.0f / stride;   // power of two: exact
    float minx = fminf(ax, fminf(bx, cx)), maxx = fmaxf(ax, fmaxf(bx, cx));
    float miny = fminf(ay, fminf(by, cy)), maxy = fmaxf(ay, fmaxf(by, cy));
    int wlo = max(0,     (int)floorf((minx - 3.0f) * inv - 0.5f) - 1);
    int whi = min(W - 1, (int)ceilf ((maxx + 3.0f) * inv - 0.5f) + 1);
    int hlo = max(0,     (int)floorf((miny - 3.0f) * inv - 0.5f) - 1);
    int hhi = min(W - 1, (int)ceilf ((maxy + 3.0f) * inv - 0.5f) + 1);
    const int ncols = max(0, whi - wlo + 1);
    const int nb = (hhi - hlo + 1 > 0) ? (hhi - hlo + 1) * ncols : 0;

    __shared__ unsigned hist[2048];
    __shared__ unsigned chunk[256];
    __shared__ unsigned s_T, s_k, s_flag;
    __shared__ unsigned tie_hw[TIE_CAP];
    __shared__ unsigned s_tiecnt;
    __shared__ double red_reg[4], red_cls[4];
    __shared__ unsigned red_pos[4];

    const int tid = threadIdx.x;
    if (tid == 0) { s_k = KCAP; s_flag = 0u; s_tiecnt = 0u; }
    __syncthreads();

    // ---- 3-pass radix select for the kth (=96th) smallest distance ----
    unsigned prefix = 0u;
    bool select_all = false;
    for (int p = 0; p < 3; ++p) {
        for (int j = tid; j < 2048; j += 256) hist[j] = 0u;
        __syncthreads();
        for (int i = tid; i < nb; i += 256) {
            int q = i / ncols;
            int w = wlo + (i - q * ncols);
            int h = hlo + q;
            float px = (w + 0.5f) * stride;
            float py = (h + 0.5f) * stride;
            bool pos; float dist;
            tri_pos_dist(px, py, ax, ay, bx, by, cx, cy, pos, dist);
            if (!pos) continue;
            unsigned bits = __float_as_uint(dist);
            unsigned bin;
            if (p == 0)      { bin = bits >> 21; }
            else if (p == 1) { if ((bits >> 21) != prefix) continue; bin = (bits >> 10) & 0x7FFu; }
            else             { if ((bits >> 10) != prefix) continue; bin = bits & 0x3FFu; }
            atomicAdd(&hist[bin], 1u);
        }
        __syncthreads();
        {
            unsigned s = 0; int base = tid * 8;
            #pragma unroll
            for (int j = 0; j < 8; ++j) s += hist[base + j];
            chunk[tid] = s;
        }
        __syncthreads();
        if (tid == 0) {
            bool doscan = true;
            if (p == 0) {
                unsigned total = 0;
                for (int t = 0; t < 256; ++t) total += chunk[t];
                if (total <= KCAP) { s_flag = 1u; doscan = false; }
            }
            if (doscan) {
                unsigned kk = s_k, cum = 0; int t = 0;
                while (cum + chunk[t] < kk) { cum += chunk[t]; ++t; }
                int bb = t * 8;
                while (cum + hist[bb] < kk) { cum += hist[bb]; ++bb; }
                s_T = (unsigned)bb;
                s_k = kk - cum;
            }
        }
        __syncthreads();
        if (s_flag) { select_all = true; break; }  // block-uniform
        if (p == 0)      prefix = s_T;
        else if (p == 1) prefix = (prefix << 11) | s_T;
        else             prefix = (prefix << 10) | s_T;
        __syncthreads();
    }
    const unsigned kth_bits = prefix;        // full 32-bit pattern of kth value
    const unsigned tie_need = s_k;           // how many of the == kth elements to take

    // ---- final pass: select, accumulate, set obj bits ----
    double regAcc = 0.0, clsAcc = 0.0;
    unsigned posAcc = 0u;

    auto contribute = [&](int hw) {
        int h = hw >> shift, w = hw & wmask;
        float px = (w + 0.5f) * stride;
        float py = (h + 0.5f) * stride;
        const float* base = pr + (size_t)b * 6 * HW + hw;
        float p0x = base[0],          p0y = base[HW];
        float p1x = base[2 * HW],     p1y = base[3 * HW];
        float p2x = base[4 * HW],     p2y = base[5 * HW];
        float g0x = (ax - px) * inv,  g0y = (ay - py) * inv;
        float g1x = (bx - px) * inv,  g1y = (by - py) * inv;
        float g2x = (cx - px) * inv,  g2y = (cy - py) * inv;
        float dx0 = p0x - g0x, dy0 = p0y - g0y;
        float p0t = dx0 * dx0 + dy0 * dy0;
        float e11x = p1x - g1x, e11y = p1y - g1y;
        float e12x = p1x - g2x, e12y = p1y - g2y;
        float e21x = p2x - g1x, e21y = p2y - g1y;
        float e22x = p2x - g2x, e22y = p2y - g2y;
        float d11 = sqrtf(e11x * e11x + e11y * e11y);
        float d12 = sqrtf(e12x * e12x + e12y * e12y);
        float d21 = sqrtf(e21x * e21x + e21y * e21y);
        float d22 = sqrtf(e22x * e22x + e22y * e22y);
        float cd = fminf(d11, d12) + fminf(d21, d22) + fminf(d11, d21) + fminf(d12, d22);
        regAcc += (double)(p0t + cd);
        clsAcc += (double)softplus_f(-pcl[(size_t)b * HW + hw]);
        posAcc += 1u;
        unsigned bi = (unsigned)(b * HW + hw);
        atomicOr(&objbits[objbase + (bi >> 5)], 1u << (bi & 31u));
    };

    for (int i = tid; i < nb; i += 256) {
        int q = i / ncols;
        int w = wlo + (i - q * ncols);
        int h = hlo + q;
        int hw = (h << shift) | w;
        float px = (w + 0.5f) * stride;
        float py = (h + 0.5f) * stride;
        bool pos; float dist;
        tri_pos_dist(px, py, ax, ay, bx, by, cx, cy, pos, dist);
        if (!pos) continue;
        if (select_all) { contribute(hw); continue; }
        unsigned bits = __float_as_uint(dist);
        if (bits < kth_bits) {
            contribute(hw);
        } else if (bits == kth_bits) {
            unsigned t = atomicAdd(&s_tiecnt, 1u);
            if (t < TIE_CAP) tie_hw[t] = (unsigned)hw;
        }
    }
    __syncthreads();
    if (!select_all) {
        unsigned n = min(s_tiecnt, (unsigned)TIE_CAP);
        for (unsigned i = tid; i < n; i += 256) {
            unsigned hw = tie_hw[i];
            unsigned rank = 0;
            for (unsigned j = 0; j < n; ++j) rank += (tie_hw[j] < hw) ? 1u : 0u;
            if (rank < tie_need) contribute((int)hw);
        }
    }

    // ---- block reduce + global accumulate ----
    for (int off = 32; off > 0; off >>= 1) {
        regAcc += __shfl_down(regAcc, off);
        clsAcc += __shfl_down(clsAcc, off);
        posAcc += __shfl_down(posAcc, off);
    }
    int wave = tid >> 6, lane = tid & 63;
    if (lane == 0) { red_reg[wave] = regAcc; red_cls[wave] = clsAcc; red_pos[wave] = posAcc; }
    __syncthreads();
    if (tid == 0) {
        atomicAdd(&sums[0], red_reg[0] + red_reg[1] + red_reg[2] + red_reg[3]);
        atomicAdd(&sums[1], red_cls[0] + red_cls[1] + red_cls[2] + red_cls[3]);
        atomicAdd(&counts[0], red_pos[0] + red_pos[1] + red_pos[2] + red_pos[3]);
    }
}

__global__ __launch_bounds__(256) void obj_kernel(
    const float* __restrict__ o0, const float* __restrict__ o1, const float* __restrict__ o2,
    const unsigned* __restrict__ objbits,
    double* __restrict__ sums, unsigned* __restrict__ counts)
{
    int idx = blockIdx.x * 256 + threadIdx.x;
    double term = 0.0; unsigned tc = 0u;
    if (idx < NTOT) {
        const float* o; int li, lbase;
        if (idx < 262144)      { o = o0; li = idx;          lbase = 0; }
        else if (idx < 327680) { o = o1; li = idx - 262144; lbase = 8192; }
        else                   { o = o2; li = idx - 327680; lbase = 10240; }
        float x = o[li];
        unsigned bit = (objbits[lbase + (li >> 5)] >> (li & 31)) & 1u;
        if (bit) { term = (double)(1.2f * softplus_f(-x)); tc = 1u; }
        else     { term = (double)softplus_f(x); }
    }
    for (int off = 32; off > 0; off >>= 1) {
        term += __shfl_down(term, off);
        tc   += __shfl_down(tc, off);
    }
    __shared__ double rterm[4]; __shared__ unsigned rtc[4];
    int wave = threadIdx.x >> 6, lane = threadIdx.x & 63;
    if (lane == 0) { rterm[wave] = term; rtc[wave] = tc; }
    __syncthreads();
    if (threadIdx.x == 0) {
        atomicAdd(&sums[2], rterm[0] + rterm[1] + rterm[2] + rterm[3]);
        atomicAdd(&counts[1], rtc[0] + rtc[1] + rtc[2] + rtc[3]);
    }
}

__global__ void finalize_kernel(const double* __restrict__ sums,
                                const unsigned* __restrict__ counts,
                                float* __restrict__ out)
{
    double reg = sums[0], cls = sums[1], obj = sums[2];
    double pc  = (double)counts[0];
    double nc  = (double)NTOT - (double)counts[1];
    double pos_eps = fmax(pc, 1.0);
    double den = pos_eps + fmax(nc, 1.0);
    out[0] = (float)(reg / pos_eps + obj / den + cls / pos_eps);
}

extern "C" void kernel_launch(void* const* d_in, const int* in_sizes, int n_in,
                              void* d_out, int out_size, void* d_ws, size_t ws_size,
                              hipStream_t stream)
{
    (void)in_sizes; (void)n_in; (void)out_size; (void)ws_size;
    const float* reg0 = (const float*)d_in[0];
    const float* obj0 = (const float*)d_in[1];
    const float* cls0 = (const float*)d_in[2];
    const float* reg1 = (const float*)d_in[3];
    const float* obj1 = (const float*)d_in[4];
    const float* cls1 = (const float*)d_in[5];
    const float* reg2 = (const float*)d_in[6];
    const float* obj2 = (const float*)d_in[7];
    const float* cls2 = (const float*)d_in[8];
    const float* gt   = (const float*)d_in[9];

    double*   sums    = (double*)d_ws;                       // 3 doubles
    unsigned* counts  = (unsigned*)((char*)d_ws + 24);       // 2 u32
    unsigned* objbits = (unsigned*)((char*)d_ws + 32);       // 10752 u32

    zero_kernel<<<43, 256, 0, stream>>>((unsigned*)d_ws, 10760);
    pair_kernel<<<1536, 256, 0, stream>>>(gt, reg0, cls0, reg1, cls1, reg2, cls2,
                                          objbits, sums, counts);
    obj_kernel<<<1344, 256, 0, stream>>>(obj0, obj1, obj2, objbits, sums, counts);
    finalize_kernel<<<1, 1, 0, stream>>>(sums, counts, (float*)d_out);
}

// Round 4
// 196.014 us; speedup vs baseline: 11.1974x; 1.3173x over previous
//
#include <hip/hip_runtime.h>

#define KCAP 96u
#define CAP 6144          // cached pos-cell list capacity; >CAP -> radix fallback
#define TIE_CAP 1024
#define NTOT 344064       // 16*(16384+4096+1024)

__device__ __forceinline__ float softplus_f(float x) {
    return fmaxf(x, 0.0f) + log1pf(expf(-fabsf(x)));
}

// Exact reproduction of the reference geometry (no fma contraction so we
// match XLA's elementwise fp32 at the selection decision boundaries).
__device__ __forceinline__ void tri_pos_dist(
    float px, float py,
    float ax, float ay, float bx, float by, float cx, float cy,
    bool& pos, float& dist)
{
#pragma clang fp contract(off)
    float d1 = (px - bx) * (ay - by) - (ax - bx) * (py - by);
    float d2 = (px - cx) * (by - cy) - (bx - cx) * (py - cy);
    float d3 = (px - ax) * (cy - ay) - (cx - ax) * (py - ay);
    bool has_neg = (d1 < 0.f) | (d2 < 0.f) | (d3 < 0.f);
    bool has_pos = (d1 > 0.f) | (d2 > 0.f) | (d3 > 0.f);
    bool inside = !(has_neg && has_pos);

    float dAB, dBC, dCA;
    {
        float vx = bx - ax, vy = by - ay, wx = px - ax, wy = py - ay;
        float t = (wx*vx + wy*vy) / (vx*vx + vy*vy + 1e-9f);
        t = fminf(fmaxf(t, 0.0f), 1.0f);
        float dx = px - (ax + t*vx), dy = py - (ay + t*vy);
        dAB = sqrtf(dx*dx + dy*dy + 1e-12f);
    }
    {
        float vx = cx - bx, vy = cy - by, wx = px - bx, wy = py - by;
        float t = (wx*vx + wy*vy) / (vx*vx + vy*vy + 1e-9f);
        t = fminf(fmaxf(t, 0.0f), 1.0f);
        float dx = px - (bx + t*vx), dy = py - (by + t*vy);
        dBC = sqrtf(dx*dx + dy*dy + 1e-12f);
    }
    {
        float vx = ax - cx, vy = ay - cy, wx = px - cx, wy = py - cy;
        float t = (wx*vx + wy*vy) / (vx*vx + vy*vy + 1e-9f);
        t = fminf(fmaxf(t, 0.0f), 1.0f);
        float dx = px - (cx + t*vx), dy = py - (cy + t*vy);
        dCA = sqrtf(dx*dx + dy*dy + 1e-12f);
    }
    dist = fminf(dAB, fminf(dBC, dCA));
    pos = inside || (dist <= 3.0f);
}

__global__ void zero_kernel(unsigned* __restrict__ p, int n) {
    int i = blockIdx.x * 256 + threadIdx.x;
    if (i < n) p[i] = 0u;
}

// One block per (level, b, g) pair. Pass A: ONE heavy pass over the
// ETA-expanded bbox, histogramming the top-11 bits of the fp32 dist pattern
// AND caching (bits, hw) of every pos cell in LDS. Common case (count<=CAP):
// the exact 32-bit kth pattern is refined from the cache with two cheap
// LDS-only passes (11+10 bits); ties are full-bit-equal (tiny), ranked by hw
// to match jax.lax.top_k. Overflow (>CAP) falls back to heavy radix passes.
__global__ __launch_bounds__(256) void pair_kernel(
    const float* __restrict__ gt,
    const float* __restrict__ reg0, const float* __restrict__ cls0,
    const float* __restrict__ reg1, const float* __restrict__ cls1,
    const float* __restrict__ reg2, const float* __restrict__ cls2,
    unsigned* __restrict__ objbits,
    double* __restrict__ sums,      // [0]=reg, [1]=cls, [2]=obj
    unsigned* __restrict__ counts)  // [0]=pos_cnt, [1]=objt_cnt
{
    const int bid = blockIdx.x;
    const int level = bid >> 9;        // 512 pairs per level
    const int pair = bid & 511;
    const int b = pair >> 5;

    int W, HW, shift, objbase;
    float stride;
    const float* pr; const float* pcl;
    if (level == 0)      { W = 128; HW = 16384; shift = 7; stride = 8.0f;  objbase = 0;     pr = reg0; pcl = cls0; }
    else if (level == 1) { W = 64;  HW = 4096;  shift = 6; stride = 16.0f; objbase = 8192;  pr = reg1; pcl = cls1; }
    else                 { W = 32;  HW = 1024;  shift = 5; stride = 32.0f; objbase = 10240; pr = reg2; pcl = cls2; }
    const int wmask = W - 1;

    const float* gp = gt + pair * 6;
    const float ax = gp[0], ay = gp[1];
    const float bx = gp[2], by = gp[3];
    const float cx = gp[4], cy = gp[5];

    // ---- expanded bbox of candidate cells (conservative, +1 cell margin) ----
    const float inv = 1.0f / stride;   // power of two: exact
    float minx = fminf(ax, fminf(bx, cx)), maxx = fmaxf(ax, fmaxf(bx, cx));
    float miny = fminf(ay, fminf(by, cy)), maxy = fmaxf(ay, fmaxf(by, cy));
    int wlo = max(0,     (int)floorf((minx - 3.0f) * inv - 0.5f) - 1);
    int whi = min(W - 1, (int)ceilf ((maxx + 3.0f) * inv - 0.5f) + 1);
    int hlo = max(0,     (int)floorf((miny - 3.0f) * inv - 0.5f) - 1);
    int hhi = min(W - 1, (int)ceilf ((maxy + 3.0f) * inv - 0.5f) + 1);
    const int ncols = max(0, whi - wlo + 1);
    const int nb = (hhi - hlo + 1 > 0) ? (hhi - hlo + 1) * ncols : 0;
    const int nbR = (nb + 255) & ~255;

    __shared__ unsigned hist[2048];
    __shared__ unsigned chunk[256];
    __shared__ unsigned s_bits[CAP];
    __shared__ unsigned short s_hw[CAP];
    __shared__ unsigned tie_hw[TIE_CAP];
    __shared__ unsigned s_cnt, s_T, s_k, s_mode, s_tiecnt;
    __shared__ double red_reg[4], red_cls[4];
    __shared__ unsigned red_pos[4];

    const int tid = threadIdx.x;
    const int lane = tid & 63;
    if (tid == 0) { s_cnt = 0u; s_tiecnt = 0u; }
    for (int j = tid; j < 2048; j += 256) hist[j] = 0u;
    __syncthreads();

    // ---- pass A: single heavy pass; histogram top-11 bits + cache pos cells ----
    for (int i = tid; i < nbR; i += 256) {
        bool pos = false; unsigned bits = 0u; int hw = 0;
        if (i < nb) {
            int q = i / ncols;
            int w = wlo + (i - q * ncols);
            int h = hlo + q;
            hw = (h << shift) | w;
            float px = (w + 0.5f) * stride;
            float py = (h + 0.5f) * stride;
            float dist;
            tri_pos_dist(px, py, ax, ay, bx, by, cx, cy, pos, dist);
            if (pos) { bits = __float_as_uint(dist); atomicAdd(&hist[bits >> 21], 1u); }
        }
        unsigned long long m = __ballot(pos);
        if (m) {
            int leader = __ffsll(m) - 1;
            unsigned base = 0u;
            if (lane == leader) base = atomicAdd(&s_cnt, (unsigned)__popcll(m));
            base = __shfl(base, leader);
            if (pos) {
                unsigned slot = base + (unsigned)__popcll(m & ((1ull << lane) - 1ull));
                if (slot < CAP) { s_bits[slot] = bits; s_hw[slot] = (unsigned short)hw; }
            }
        }
    }
    __syncthreads();

    {   // chunk-reduce the histogram
        unsigned s = 0; int base = tid * 8;
        #pragma unroll
        for (int j = 0; j < 8; ++j) s += hist[base + j];
        chunk[tid] = s;
    }
    __syncthreads();
    if (tid == 0) {
        unsigned total = s_cnt;
        if (total <= KCAP) {
            s_mode = 1u;                       // select everything (all cached)
        } else {
            s_mode = (total <= CAP) ? 0u : 2u;
            unsigned kk = KCAP, cum = 0; int t = 0;
            while (cum + chunk[t] < kk) { cum += chunk[t]; ++t; }
            int bb = t * 8;
            while (cum + hist[bb] < kk) { cum += hist[bb]; ++bb; }
            s_T = (unsigned)bb;
            s_k = kk - cum;
        }
    }
    __syncthreads();
    const unsigned mode = s_mode;
    const unsigned n = min(s_cnt, (unsigned)CAP);
    unsigned kth_bits = 0u, tie_need = 0u;

    if (mode == 0u) {
        // ---- exact kth via 2 cheap LDS-only refinement passes over cache ----
        unsigned prefix = s_T;               // top 11 bits
        // pass 1: bits[20:10]
        __syncthreads();
        for (int j = tid; j < 2048; j += 256) hist[j] = 0u;
        __syncthreads();
        for (unsigned i = tid; i < n; i += 256) {
            unsigned bi = s_bits[i];
            if ((bi >> 21) == prefix) atomicAdd(&hist[(bi >> 10) & 0x7FFu], 1u);
        }
        __syncthreads();
        { unsigned s = 0; int base = tid * 8;
          #pragma unroll
          for (int j = 0; j < 8; ++j) s += hist[base + j];
          chunk[tid] = s; }
        __syncthreads();
        if (tid == 0) {
            unsigned kk = s_k, cum = 0; int t = 0;
            while (cum + chunk[t] < kk) { cum += chunk[t]; ++t; }
            int bb = t * 8;
            while (cum + hist[bb] < kk) { cum += hist[bb]; ++bb; }
            s_T = (unsigned)bb;
            s_k = kk - cum;
        }
        __syncthreads();
        prefix = (prefix << 11) | s_T;       // top 22 bits
        // pass 2: bits[9:0]
        __syncthreads();
        for (int j = tid; j < 2048; j += 256) hist[j] = 0u;
        __syncthreads();
        for (unsigned i = tid; i < n; i += 256) {
            unsigned bi = s_bits[i];
            if ((bi >> 10) == prefix) atomicAdd(&hist[bi & 0x3FFu], 1u);
        }
        __syncthreads();
        { unsigned s = 0; int base = tid * 8;
          #pragma unroll
          for (int j = 0; j < 8; ++j) s += hist[base + j];
          chunk[tid] = s; }
        __syncthreads();
        if (tid == 0) {
            unsigned kk = s_k, cum = 0; int t = 0;
            while (cum + chunk[t] < kk) { cum += chunk[t]; ++t; }
            int bb = t * 8;
            while (cum + hist[bb] < kk) { cum += hist[bb]; ++bb; }
            s_T = (unsigned)bb;
            s_k = kk - cum;
        }
        __syncthreads();
        kth_bits = (prefix << 10) | s_T;     // full 32-bit kth pattern
        tie_need = s_k;
    }

    // ---- contribution ----
    double regAcc = 0.0, clsAcc = 0.0;
    unsigned posAcc = 0u;

    auto contribute = [&](int hw) {
        int h = hw >> shift, w = hw & wmask;
        float px = (w + 0.5f) * stride;
        float py = (h + 0.5f) * stride;
        const float* base = pr + (size_t)b * 6 * HW + hw;
        float p0x = base[0],          p0y = base[HW];
        float p1x = base[2 * HW],     p1y = base[3 * HW];
        float p2x = base[4 * HW],     p2y = base[5 * HW];
        float g0x = (ax - px) * inv,  g0y = (ay - py) * inv;
        float g1x = (bx - px) * inv,  g1y = (by - py) * inv;
        float g2x = (cx - px) * inv,  g2y = (cy - py) * inv;
        float dx0 = p0x - g0x, dy0 = p0y - g0y;
        float p0t = dx0 * dx0 + dy0 * dy0;
        float e11x = p1x - g1x, e11y = p1y - g1y;
        float e12x = p1x - g2x, e12y = p1y - g2y;
        float e21x = p2x - g1x, e21y = p2y - g1y;
        float e22x = p2x - g2x, e22y = p2y - g2y;
        float d11 = sqrtf(e11x * e11x + e11y * e11y);
        float d12 = sqrtf(e12x * e12x + e12y * e12y);
        float d21 = sqrtf(e21x * e21x + e21y * e21y);
        float d22 = sqrtf(e22x * e22x + e22y * e22y);
        float cd = fminf(d11, d12) + fminf(d21, d22) + fminf(d11, d21) + fminf(d12, d22);
        regAcc += (double)(p0t + cd);
        clsAcc += (double)softplus_f(-pcl[(size_t)b * HW + hw]);
        posAcc += 1u;
        unsigned bi = (unsigned)(b * HW + hw);
        atomicOr(&objbits[objbase + (bi >> 5)], 1u << (bi & 31u));
    };

    if (mode == 1u) {
        for (unsigned i = tid; i < n; i += 256) contribute((int)s_hw[i]);
    } else if (mode == 0u) {
        for (unsigned i = tid; i < n; i += 256) {
            unsigned bi = s_bits[i];
            if (bi < kth_bits) {
                contribute((int)s_hw[i]);
            } else if (bi == kth_bits) {
                unsigned t = atomicAdd(&s_tiecnt, 1u);
                if (t < TIE_CAP) tie_hw[t] = s_hw[i];
            }
        }
        __syncthreads();
        unsigned tn = min(s_tiecnt, (unsigned)TIE_CAP);
        for (unsigned i = tid; i < tn; i += 256) {
            unsigned hwv = tie_hw[i], rank = 0;
            for (unsigned j = 0; j < tn; ++j) rank += (tie_hw[j] < hwv) ? 1u : 0u;
            if (rank < tie_need) contribute((int)hwv);
        }
    } else {
        // ---- rare fallback (>CAP pos cells): heavy radix p=1,2 + final pass ----
        unsigned prefix = s_T;
        for (int p = 1; p < 3; ++p) {
            __syncthreads();
            for (int j = tid; j < 2048; j += 256) hist[j] = 0u;
            __syncthreads();
            for (int i = tid; i < nb; i += 256) {
                int q = i / ncols;
                int w = wlo + (i - q * ncols);
                int h = hlo + q;
                float px = (w + 0.5f) * stride;
                float py = (h + 0.5f) * stride;
                bool pos; float dist;
                tri_pos_dist(px, py, ax, ay, bx, by, cx, cy, pos, dist);
                if (!pos) continue;
                unsigned bits = __float_as_uint(dist);
                unsigned bin;
                if (p == 1) { if ((bits >> 21) != prefix) continue; bin = (bits >> 10) & 0x7FFu; }
                else        { if ((bits >> 10) != prefix) continue; bin = bits & 0x3FFu; }
                atomicAdd(&hist[bin], 1u);
            }
            __syncthreads();
            { unsigned s = 0; int base = tid * 8;
              #pragma unroll
              for (int j = 0; j < 8; ++j) s += hist[base + j];
              chunk[tid] = s; }
            __syncthreads();
            if (tid == 0) {
                unsigned kk = s_k, cum = 0; int t = 0;
                while (cum + chunk[t] < kk) { cum += chunk[t]; ++t; }
                int bb = t * 8;
                while (cum + hist[bb] < kk) { cum += hist[bb]; ++bb; }
                s_T = (unsigned)bb;
                s_k = kk - cum;
            }
            __syncthreads();
            prefix = (p == 1) ? ((prefix << 11) | s_T) : ((prefix << 10) | s_T);
        }
        const unsigned kth = prefix, need = s_k;
        for (int i = tid; i < nb; i += 256) {
            int q = i / ncols;
            int w = wlo + (i - q * ncols);
            int h = hlo + q;
            int hw = (h << shift) | w;
            float px = (w + 0.5f) * stride;
            float py = (h + 0.5f) * stride;
            bool pos; float dist;
            tri_pos_dist(px, py, ax, ay, bx, by, cx, cy, pos, dist);
            if (!pos) continue;
            unsigned bits = __float_as_uint(dist);
            if (bits < kth) {
                contribute(hw);
            } else if (bits == kth) {
                unsigned t = atomicAdd(&s_tiecnt, 1u);
                if (t < TIE_CAP) tie_hw[t] = (unsigned)hw;
            }
        }
        __syncthreads();
        unsigned tn = min(s_tiecnt, (unsigned)TIE_CAP);
        for (unsigned i = tid; i < tn; i += 256) {
            unsigned hwv = tie_hw[i], rank = 0;
            for (unsigned j = 0; j < tn; ++j) rank += (tie_hw[j] < hwv) ? 1u : 0u;
            if (rank < need) contribute((int)hwv);
        }
    }

    // ---- block reduce + global accumulate ----
    for (int off = 32; off > 0; off >>= 1) {
        regAcc += __shfl_down(regAcc, off);
        clsAcc += __shfl_down(clsAcc, off);
        posAcc += __shfl_down(posAcc, off);
    }
    int wave = tid >> 6;
    if (lane == 0) { red_reg[wave] = regAcc; red_cls[wave] = clsAcc; red_pos[wave] = posAcc; }
    __syncthreads();
    if (tid == 0) {
        atomicAdd(&sums[0], red_reg[0] + red_reg[1] + red_reg[2] + red_reg[3]);
        atomicAdd(&sums[1], red_cls[0] + red_cls[1] + red_cls[2] + red_cls[3]);
        atomicAdd(&counts[0], red_pos[0] + red_pos[1] + red_pos[2] + red_pos[3]);
    }
}

__global__ __launch_bounds__(256) void obj_kernel(
    const float* __restrict__ o0, const float* __restrict__ o1, const float* __restrict__ o2,
    const unsigned* __restrict__ objbits,
    double* __restrict__ sums, unsigned* __restrict__ counts)
{
    int idx = blockIdx.x * 256 + threadIdx.x;
    double term = 0.0; unsigned tc = 0u;
    if (idx < NTOT) {
        const float* o; int li, lbase;
        if (idx < 262144)      { o = o0; li = idx;          lbase = 0; }
        else if (idx < 327680) { o = o1; li = idx - 262144; lbase = 8192; }
        else                   { o = o2; li = idx - 327680; lbase = 10240; }
        float x = o[li];
        unsigned bit = (objbits[lbase + (li >> 5)] >> (li & 31)) & 1u;
        if (bit) { term = (double)(1.2f * softplus_f(-x)); tc = 1u; }
        else     { term = (double)softplus_f(x); }
    }
    for (int off = 32; off > 0; off >>= 1) {
        term += __shfl_down(term, off);
        tc   += __shfl_down(tc, off);
    }
    __shared__ double rterm[4]; __shared__ unsigned rtc[4];
    int wave = threadIdx.x >> 6, lane = threadIdx.x & 63;
    if (lane == 0) { rterm[wave] = term; rtc[wave] = tc; }
    __syncthreads();
    if (threadIdx.x == 0) {
        atomicAdd(&sums[2], rterm[0] + rterm[1] + rterm[2] + rterm[3]);
        atomicAdd(&counts[1], rtc[0] + rtc[1] + rtc[2] + rtc[3]);
    }
}

__global__ void finalize_kernel(const double* __restrict__ sums,
                                const unsigned* __restrict__ counts,
                                float* __restrict__ out)
{
    double reg = sums[0], cls = sums[1], obj = sums[2];
    double pc  = (double)counts[0];
    double nc  = (double)NTOT - (double)counts[1];
    double pos_eps = fmax(pc, 1.0);
    double den = pos_eps + fmax(nc, 1.0);
    out[0] = (float)(reg / pos_eps + obj / den + cls / pos_eps);
}

extern "C" void kernel_launch(void* const* d_in, const int* in_sizes, int n_in,
                              void* d_out, int out_size, void* d_ws, size_t ws_size,
                              hipStream_t stream)
{
    (void)in_sizes; (void)n_in; (void)out_size; (void)ws_size;
    const float* reg0 = (const float*)d_in[0];
    const float* obj0 = (const float*)d_in[1];
    const float* cls0 = (const float*)d_in[2];
    const float* reg1 = (const float*)d_in[3];
    const float* obj1 = (const float*)d_in[4];
    const float* cls1 = (const float*)d_in[5];
    const float* reg2 = (const float*)d_in[6];
    const float* obj2 = (const float*)d_in[7];
    const float* cls2 = (const float*)d_in[8];
    const float* gt   = (const float*)d_in[9];

    double*   sums    = (double*)d_ws;                       // 3 doubles
    unsigned* counts  = (unsigned*)((char*)d_ws + 24);       // 2 u32
    unsigned* objbits = (unsigned*)((char*)d_ws + 32);       // 10752 u32

    zero_kernel<<<43, 256, 0, stream>>>((unsigned*)d_ws, 10760);
    pair_kernel<<<1536, 256, 0, stream>>>(gt, reg0, cls0, reg1, cls1, reg2, cls2,
                                          objbits, sums, counts);
    obj_kernel<<<1344, 256, 0, stream>>>(obj0, obj1, obj2, objbits, sums, counts);
    finalize_kernel<<<1, 1, 0, stream>>>(sums, counts, (float*)d_out);
}